// Round 7
// baseline (606.939 us; speedup 1.0000x reference)
//
#include <hip/hip_runtime.h>
#include <hip/hip_cooperative_groups.h>
#include <math.h>

namespace cgx = cooperative_groups;

// Quantized softmax over axis 1 of x(8, 4096, 1024) fp32.
// Groups: (b, c) column, 8192 groups of 4096 elements (stride 1024 floats).
//
// Round-7 design: ONE cooperative kernel, 1024 blocks x 512 thr = 4 blocks/CU
// (32 waves/CU), NO big LDS (occupancy not LDS-capped; round 5's 128KB slab
// capped us at 16 waves -> latency-bound 109us; round 6's LDS LUT gather hit
// 4.5M bank conflicts -> 190us). Codes in global ws (32MB, same-block write
// then read -> L2/L3 hot). 5 streaming phases, 4 grid syncs. All cross-block
// scalars via small ws arrays + redundant per-block re-reduction: NO float
// atomics, deterministic. Bulk arrays in [chunk][group] layout -> coalesced.

typedef float       f4 __attribute__((ext_vector_type(4)));
typedef signed char c4 __attribute__((ext_vector_type(4)));

static constexpr int Bdim = 8;
static constexpr int Jdim = 4096;
static constexpr int Cdim = 1024;
static constexpr int NG   = Bdim * Cdim;     // 8192 groups

// ---- fused geometry ----
static constexpr int FGRID = 1024;           // blocks: (b, 32-row chunk)
static constexpr int FBLK  = 512;            // 8 waves
static constexpr int NJC32 = 128;            // 32-row chunks per batch
static constexpr int NCH   = 256;            // 16-row chunks per group

// ---- ws layout (byte offsets) ----
static constexpr size_t GMV_OFF  = 0;                      // f32[8192] group max VALUE
static constexpr size_t DG_OFF   = 32768;                  // f32[8192] per-group d
static constexpr size_t SARR_OFF = 65536;                  // f32[8192] group sums
static constexpr size_t PMAX_OFF = 131072;                 // i8[256][8192]
static constexpr size_t PMIN_OFF = PMAX_OFF + 2097152;     // i8[256][8192]
static constexpr size_t PSUM_OFF = PMIN_OFF + 2097152;     // f32[256][8192] = 8MB
static constexpr size_t CODES_OFF = 16u * 1024 * 1024;     // i8[8][4096][1024] = 32MB
static constexpr size_t WS_NEED   = CODES_OFF + 33554432;  // 48MB

__device__ __forceinline__ float code8f(float x, float sinv) {
    // int8 code as float; rintf = round-half-even matches jnp.round
    return fminf(fmaxf(rintf(x * sinv), -128.0f), 127.0f);
}
// e_q = fq16(exp(fq16(clip(xq - gmax, -12, 0)))); scale_e = 1/32767 exactly
// (group-max element has sub==0 -> e==1). 16-bit clamps provably inactive.
__device__ __forceinline__ float eq_from(float xq, float gmv, float ssub_inv, float ssub) {
    float sub = fminf(fmaxf(xq - gmv, -12.0f), 0.0f);
    float q   = rintf(sub * ssub_inv);
    float e   = __expf(q * ssub);
    return rintf(e * 32767.0f) * (1.0f / 32767.0f);
}
__device__ __forceinline__ f4 fmax4v(f4 a, f4 b) {
    f4 r; r[0]=fmaxf(a[0],b[0]); r[1]=fmaxf(a[1],b[1]);
    r[2]=fmaxf(a[2],b[2]); r[3]=fmaxf(a[3],b[3]); return r;
}
__device__ __forceinline__ f4 fmin4v(f4 a, f4 b) {
    f4 r; r[0]=fminf(a[0],b[0]); r[1]=fminf(a[1],b[1]);
    r[2]=fminf(a[2],b[2]); r[3]=fminf(a[3],b[3]); return r;
}

__global__ __launch_bounds__(FBLK, 8) void k_fused(const float* __restrict__ x,
                                                   const float* __restrict__ scale,
                                                   float* __restrict__ out,
                                                   char* __restrict__ ws) {
    const int bid   = blockIdx.x;
    const int b     = bid >> 7;          // batch 0..7
    const int jc    = bid & 127;         // 32-row chunk
    const int t     = threadIdx.x;
    const int rhalf = t >> 8;            // 0/1: which 16-row half
    const int c0    = (t & 255) * 4;     // 4 columns per thread
    const int w     = t >> 6;            // wave 0..7
    const int l     = t & 63;            // lane
    const int ch    = jc * 2 + rhalf;    // 16-row chunk index 0..255
    const float s    = scale[0];
    const float sinv = 1.0f / s;

    float*       gmv   = (float*)(ws + GMV_OFF);
    float*       dg    = (float*)(ws + DG_OFF);
    float*       sarr  = (float*)(ws + SARR_OFF);
    signed char* pmax8 = (signed char*)(ws + PMAX_OFF);
    signed char* pmin8 = (signed char*)(ws + PMIN_OFF);
    float*       psum  = (float*)(ws + PSUM_OFF);
    signed char* codes = (signed char*)(ws + CODES_OFF);

    __shared__ float lredA[8], lredB[8], bc[3];

    const int    row0 = jc * 32 + rhalf * 16;
    const size_t base = ((size_t)(b * Jdim + row0)) * Cdim + c0;

    // ---------- P1: read x (NT), quantize, write codes + per-(ch,col) max/min
    {
        f4 vmax = {-1e30f, -1e30f, -1e30f, -1e30f};
        f4 vmin = { 1e30f,  1e30f,  1e30f,  1e30f};
#pragma unroll 4
        for (int r = 0; r < 16; ++r) {
            const f4 v = __builtin_nontemporal_load(
                reinterpret_cast<const f4*>(x + base + (size_t)r * Cdim));
            f4 q;
            q[0] = code8f(v[0], sinv); q[1] = code8f(v[1], sinv);
            q[2] = code8f(v[2], sinv); q[3] = code8f(v[3], sinv);
            vmax = fmax4v(vmax, q); vmin = fmin4v(vmin, q);
            *reinterpret_cast<c4*>(codes + base + (size_t)r * Cdim) =
                (c4){(signed char)(int)q[0], (signed char)(int)q[1],
                     (signed char)(int)q[2], (signed char)(int)q[3]};
        }
        const size_t pidx = (size_t)ch * NG + b * Cdim + c0;   // [ch][g] coalesced
        *reinterpret_cast<c4*>(pmax8 + pidx) =
            (c4){(signed char)(int)vmax[0], (signed char)(int)vmax[1],
                 (signed char)(int)vmax[2], (signed char)(int)vmax[3]};
        *reinterpret_cast<c4*>(pmin8 + pidx) =
            (c4){(signed char)(int)vmin[0], (signed char)(int)vmin[1],
                 (signed char)(int)vmin[2], (signed char)(int)vmin[3]};
    }
    cgx::this_grid().sync();

    // ---------- P2: wave per group -> group gmax value + d = min(12, range)
    {
        const int g = bid * 8 + w;        // 1024 blocks x 8 waves = 8192 groups
        int mx = -128, mn = 127;
#pragma unroll
        for (int j = 0; j < 4; ++j) {
            const size_t idx = (size_t)(l * 4 + j) * NG + g;
            mx = max(mx, (int)pmax8[idx]);
            mn = min(mn, (int)pmin8[idx]);
        }
#pragma unroll
        for (int off = 1; off < 64; off <<= 1) {
            mx = max(mx, __shfl_xor(mx, off));
            mn = min(mn, __shfl_xor(mn, off));
        }
        if (l == 0) {
            gmv[g] = (float)mx * s;                                // == ref max(xq)
            dg[g]  = fminf(12.0f, (float)mx * s - (float)mn * s);  // range, exact fp
        }
    }
    cgx::this_grid().sync();

    // ---------- P3: amax (redundant per block); e_q partial sums per (ch, col)
    {
        float m = 0.0f;
#pragma unroll
        for (int i = 0; i < 4; ++i) {
            const f4 dv = *reinterpret_cast<const f4*>(dg + t * 16 + i * 4);
            m = fmaxf(fmaxf(fmaxf(dv[0], dv[1]), fmaxf(dv[2], dv[3])), m);
        }
#pragma unroll
        for (int off = 1; off < 64; off <<= 1) m = fmaxf(m, __shfl_xor(m, off));
        if (l == 0) lredA[w] = m;
        __syncthreads();
        if (t == 0) {
            float mm = lredA[0];
#pragma unroll
            for (int i = 1; i < 8; ++i) mm = fmaxf(mm, lredA[i]);
            bc[0] = mm;
        }
        __syncthreads();
    }
    const float amax = fmaxf(bc[0], 1e-9f);
    const float ssub = amax / 32767.0f;
    const float ssub_inv = 1.0f / ssub;
    const f4 gm4 = *reinterpret_cast<const f4*>(gmv + b * Cdim + c0);
    {
        f4 acc = {0.f, 0.f, 0.f, 0.f};
#pragma unroll 4
        for (int r = 0; r < 16; ++r) {
            const c4 q = *reinterpret_cast<const c4*>(codes + base + (size_t)r * Cdim);
            acc[0] += eq_from((float)q[0] * s, gm4[0], ssub_inv, ssub);
            acc[1] += eq_from((float)q[1] * s, gm4[1], ssub_inv, ssub);
            acc[2] += eq_from((float)q[2] * s, gm4[2], ssub_inv, ssub);
            acc[3] += eq_from((float)q[3] * s, gm4[3], ssub_inv, ssub);
        }
        *reinterpret_cast<f4*>(psum + (size_t)ch * NG + b * Cdim + c0) = acc;
    }
    cgx::this_grid().sync();

    // ---------- P4: wave per group -> group sum (fixed butterfly order)
    {
        const int g = bid * 8 + w;
        float sum = 0.0f;
#pragma unroll
        for (int j = 0; j < 4; ++j)
            sum += psum[(size_t)(l * 4 + j) * NG + g];
#pragma unroll
        for (int off = 1; off < 64; off <<= 1) sum += __shfl_xor(sum, off);
        if (l == 0) sarr[g] = sum;
    }
    cgx::this_grid().sync();

    // ---------- P5: global max/min s (redundant); derive scales; write out
    {
        float mx = -1e30f, mn = 1e30f;
#pragma unroll
        for (int i = 0; i < 4; ++i) {
            const f4 sv = *reinterpret_cast<const f4*>(sarr + t * 16 + i * 4);
            mx = fmaxf(fmaxf(fmaxf(sv[0], sv[1]), fmaxf(sv[2], sv[3])), mx);
            mn = fminf(fminf(fminf(sv[0], sv[1]), fminf(sv[2], sv[3])), mn);
        }
#pragma unroll
        for (int off = 1; off < 64; off <<= 1) {
            mx = fmaxf(mx, __shfl_xor(mx, off));
            mn = fminf(mn, __shfl_xor(mn, off));
        }
        if (l == 0) { lredA[w] = mx; lredB[w] = mn; }
        __syncthreads();
        if (t == 0) {
            float gmx = lredA[0], gmn = lredB[0];
#pragma unroll
            for (int i = 1; i < 8; ++i) {
                gmx = fmaxf(gmx, lredA[i]); gmn = fminf(gmn, lredB[i]);
            }
            bc[1] = gmx; bc[2] = gmn;
        }
        __syncthreads();
    }
    const float max_s = bc[1], min_s = bc[2];
    // fq monotone: min s_q = fq(min s); max r = 1/min s_q; max r_q = fq(max r)
    const float scale_s = fmaxf(max_s, 1e-9f) / 32767.0f;
    const float ss_inv  = 1.0f / scale_s;
    const float minsq   = fminf(fmaxf(rintf(min_s * ss_inv), -32768.0f), 32767.0f) * scale_s;
    const float maxr    = 1.0f / minsq;
    const float scale_r = fmaxf(maxr, 1e-9f) / 32767.0f;
    const float sr_inv  = 1.0f / scale_r;
    const float maxrq   = fminf(fmaxf(rintf(maxr * sr_inv), -32768.0f), 32767.0f) * scale_r;
    const float scale_out = fmaxf(maxrq, 1e-9f) / 127.0f;
    const float so_inv  = 1.0f / scale_out;

    const f4 s4 = *reinterpret_cast<const f4*>(sarr + b * Cdim + c0);
    f4 rq;
#pragma unroll
    for (int i = 0; i < 4; ++i) {
        float qv = fminf(fmaxf(rintf(s4[i] * ss_inv), -32768.0f), 32767.0f) * scale_s;
        rq[i] = fminf(fmaxf(rintf((1.0f / qv) * sr_inv), -32768.0f), 32767.0f) * scale_r;
    }
#pragma unroll 4
    for (int r = 0; r < 16; ++r) {
        const c4 q = *reinterpret_cast<const c4*>(codes + base + (size_t)r * Cdim);
        const float e0 = eq_from((float)q[0] * s, gm4[0], ssub_inv, ssub) * rq[0];
        const float e1 = eq_from((float)q[1] * s, gm4[1], ssub_inv, ssub) * rq[1];
        const float e2 = eq_from((float)q[2] * s, gm4[2], ssub_inv, ssub) * rq[2];
        const float e3 = eq_from((float)q[3] * s, gm4[3], ssub_inv, ssub) * rq[3];
        f4 o;
        o[0] = fminf(fmaxf(rintf(e0 * so_inv), -128.0f), 127.0f) * scale_out;
        o[1] = fminf(fmaxf(rintf(e1 * so_inv), -128.0f), 127.0f) * scale_out;
        o[2] = fminf(fmaxf(rintf(e2 * so_inv), -128.0f), 127.0f) * scale_out;
        o[3] = fminf(fmaxf(rintf(e3 * so_inv), -128.0f), 127.0f) * scale_out;
        __builtin_nontemporal_store(o,
            reinterpret_cast<f4*>(out + base + (size_t)r * Cdim));
    }
}

// ======================= round-3 fallback path (proven, 101 us) =======================
static constexpr int JCHUNK = 16;
static constexpr int NJC = Jdim / JCHUNK;
static constexpr int PSIZE = Bdim * NJC * Cdim;

static constexpr int SC_OFF   = 0;
static constexpr int GMAX_OFF = 16;
static constexpr int S_OFF    = GMAX_OFF + NG;
static constexpr int PS_OFF   = S_OFF + NG;
static constexpr size_t FB_BYTES    = ((size_t)PS_OFF + PSIZE) * 4;
static constexpr size_t CODES_BYTES = (size_t)Bdim * Jdim * Cdim;
static constexpr size_t P_BYTES     = 2 * (size_t)PSIZE;

template <bool WC>
__global__ __launch_bounds__(256) void k_pass1(const float* __restrict__ x,
                                               const float* __restrict__ scale,
                                               float* __restrict__ fbuf,
                                               signed char* __restrict__ codes,
                                               signed char* __restrict__ pmax,
                                               signed char* __restrict__ pmin) {
    if (blockIdx.x == 0 && threadIdx.x == 0) {
        fbuf[SC_OFF + 0] = 0.0f;
        fbuf[SC_OFF + 1] = 0.0f;
        fbuf[SC_OFF + 2] = __int_as_float(0x7f800000);
    }
    const int b  = blockIdx.x / NJC;
    const int jc = blockIdx.x % NJC;
    const int c0 = threadIdx.x * 4;
    const float sinv = 1.0f / scale[0];
    const size_t base = ((size_t)(b * Jdim + jc * JCHUNK)) * Cdim + c0;

    f4 vmax = {-1e30f, -1e30f, -1e30f, -1e30f};
    f4 vmin = { 1e30f,  1e30f,  1e30f,  1e30f};
    #pragma unroll 4
    for (int r = 0; r < JCHUNK; ++r) {
        const f4 v = __builtin_nontemporal_load(
            reinterpret_cast<const f4*>(x + base + (size_t)r * Cdim));
        f4 q;
        q[0] = code8f(v[0], sinv); q[1] = code8f(v[1], sinv);
        q[2] = code8f(v[2], sinv); q[3] = code8f(v[3], sinv);
        vmax = fmax4v(vmax, q); vmin = fmin4v(vmin, q);
        if (WC) {
            c4 pk = {(signed char)(int)q[0], (signed char)(int)q[1],
                     (signed char)(int)q[2], (signed char)(int)q[3]};
            *reinterpret_cast<c4*>(codes + base + (size_t)r * Cdim) = pk;
        }
    }
    const size_t pidx = ((size_t)(b * NJC + jc)) * Cdim + c0;
    c4 mx = {(signed char)(int)vmax[0], (signed char)(int)vmax[1],
             (signed char)(int)vmax[2], (signed char)(int)vmax[3]};
    c4 mn = {(signed char)(int)vmin[0], (signed char)(int)vmin[1],
             (signed char)(int)vmin[2], (signed char)(int)vmin[3]};
    *reinterpret_cast<c4*>(pmax + pidx) = mx;
    *reinterpret_cast<c4*>(pmin + pidx) = mn;
}

__global__ __launch_bounds__(256) void k_reduce1(const float* __restrict__ scale,
                                                 float* __restrict__ fbuf,
                                                 const signed char* __restrict__ pmax,
                                                 const signed char* __restrict__ pmin) {
    const int b   = blockIdx.x / 32;
    const int ct  = blockIdx.x % 32;
    const int ci  = threadIdx.x & 31;
    const int sub = threadIdx.x >> 5;
    const int c   = ct * 32 + ci;

    int mx = -128, mn = 127;
    for (int jc = sub; jc < NJC; jc += 8) {
        const size_t idx = ((size_t)(b * NJC + jc)) * Cdim + c;
        mx = max(mx, (int)pmax[idx]);
        mn = min(mn, (int)pmin[idx]);
    }
    __shared__ int smx[8][32], smn[8][32];
    smx[sub][ci] = mx; smn[sub][ci] = mn;
    __syncthreads();
    for (int off = 4; off; off >>= 1) {
        if (sub < off) {
            smx[sub][ci] = max(smx[sub][ci], smx[sub + off][ci]);
            smn[sub][ci] = min(smn[sub][ci], smn[sub + off][ci]);
        }
        __syncthreads();
    }
    __shared__ float sd[32];
    if (sub == 0) {
        const float s = scale[0];
        fbuf[GMAX_OFF + b * Cdim + c] = (float)smx[0][ci];
        sd[ci] = fminf(12.0f, (float)smx[0][ci] * s - (float)smn[0][ci] * s);
    }
    __syncthreads();
    if (threadIdx.x == 0) {
        float m = sd[0];
        #pragma unroll
        for (int i = 1; i < 32; ++i) m = fmaxf(m, sd[i]);
        atomicMax(reinterpret_cast<unsigned int*>(fbuf + SC_OFF + 0), __float_as_uint(m));
    }
}

template <bool UC>
__global__ __launch_bounds__(256) void k_pass2(const float* __restrict__ x,
                                               const signed char* __restrict__ codes,
                                               const float* __restrict__ scale,
                                               float* __restrict__ fbuf) {
    const int b  = blockIdx.x / NJC;
    const int jc = blockIdx.x % NJC;
    const int c0 = threadIdx.x * 4;
    const float s = scale[0];
    const float sinv = 1.0f / s;
    const float amax = fmaxf(fbuf[SC_OFF + 0], 1e-9f);
    const float ssub = amax / 32767.0f;
    const float ssub_inv = 1.0f / ssub;
    const f4 gmc = *reinterpret_cast<const f4*>(fbuf + GMAX_OFF + b * Cdim + c0);
    const float gm0 = gmc[0]*s, gm1 = gmc[1]*s, gm2 = gmc[2]*s, gm3 = gmc[3]*s;
    const size_t base = ((size_t)(b * Jdim + jc * JCHUNK)) * Cdim + c0;

    float a0 = 0.f, a1 = 0.f, a2 = 0.f, a3 = 0.f;
    #pragma unroll 4
    for (int r = 0; r < JCHUNK; ++r) {
        float xq0, xq1, xq2, xq3;
        if (UC) {
            const c4 q = *reinterpret_cast<const c4*>(codes + base + (size_t)r * Cdim);
            xq0 = (float)q[0]*s; xq1 = (float)q[1]*s; xq2 = (float)q[2]*s; xq3 = (float)q[3]*s;
        } else {
            const f4 v = *reinterpret_cast<const f4*>(x + base + (size_t)r * Cdim);
            xq0 = code8f(v[0], sinv)*s; xq1 = code8f(v[1], sinv)*s;
            xq2 = code8f(v[2], sinv)*s; xq3 = code8f(v[3], sinv)*s;
        }
        a0 += eq_from(xq0, gm0, ssub_inv, ssub);
        a1 += eq_from(xq1, gm1, ssub_inv, ssub);
        a2 += eq_from(xq2, gm2, ssub_inv, ssub);
        a3 += eq_from(xq3, gm3, ssub_inv, ssub);
    }
    f4 acc = {a0, a1, a2, a3};
    *reinterpret_cast<f4*>(fbuf + PS_OFF + ((size_t)(b * NJC + jc)) * Cdim + c0) = acc;
}

__global__ __launch_bounds__(256) void k_reduce2(float* __restrict__ fbuf) {
    const int b   = blockIdx.x / 32;
    const int ct  = blockIdx.x % 32;
    const int ci  = threadIdx.x & 31;
    const int sub = threadIdx.x >> 5;
    const int c   = ct * 32 + ci;

    float p = 0.0f;
    for (int jc = sub; jc < NJC; jc += 8)
        p += fbuf[PS_OFF + ((size_t)(b * NJC + jc)) * Cdim + c];
    __shared__ float sp[8][32];
    sp[sub][ci] = p;
    __syncthreads();
    for (int off = 4; off; off >>= 1) {
        if (sub < off) sp[sub][ci] += sp[sub + off][ci];
        __syncthreads();
    }
    __shared__ float smx[32], smn[32];
    if (sub == 0) {
        const float tv = sp[0][ci];
        fbuf[S_OFF + b * Cdim + c] = tv;
        smx[ci] = tv; smn[ci] = tv;
    }
    __syncthreads();
    if (threadIdx.x == 0) {
        float mx = smx[0], mn = smn[0];
        #pragma unroll
        for (int i = 1; i < 32; ++i) { mx = fmaxf(mx, smx[i]); mn = fminf(mn, smn[i]); }
        atomicMax(reinterpret_cast<unsigned int*>(fbuf + SC_OFF + 1), __float_as_uint(mx));
        atomicMin(reinterpret_cast<unsigned int*>(fbuf + SC_OFF + 2), __float_as_uint(mn));
    }
}

template <bool UC>
__global__ __launch_bounds__(256) void k_pass3(const float* __restrict__ x,
                                               const signed char* __restrict__ codes,
                                               const float* __restrict__ scale,
                                               const float* __restrict__ fbuf,
                                               float* __restrict__ out) {
    const int b  = blockIdx.x / NJC;
    const int jc = blockIdx.x % NJC;
    const int c0 = threadIdx.x * 4;
    const float s = scale[0];
    const float sinv = 1.0f / s;

    const float amax = fmaxf(fbuf[SC_OFF + 0], 1e-9f);
    const float ssub = amax / 32767.0f;
    const float ssub_inv = 1.0f / ssub;

    const float max_s = fbuf[SC_OFF + 1];
    const float min_s = fbuf[SC_OFF + 2];
    const float scale_s = fmaxf(max_s, 1e-9f) / 32767.0f;
    const float ss_inv = 1.0f / scale_s;
    const float minsq = fminf(fmaxf(rintf(min_s * ss_inv), -32768.0f), 32767.0f) * scale_s;
    const float maxr  = 1.0f / minsq;
    const float scale_r = fmaxf(maxr, 1e-9f) / 32767.0f;
    const float sr_inv  = 1.0f / scale_r;
    const float maxrq = fminf(fmaxf(rintf(maxr * sr_inv), -32768.0f), 32767.0f) * scale_r;
    const float scale_out = fmaxf(maxrq, 1e-9f) / 127.0f;
    const float so_inv = 1.0f / scale_out;

    const f4 gmc = *reinterpret_cast<const f4*>(fbuf + GMAX_OFF + b * Cdim + c0);
    const float gm0 = gmc[0]*s, gm1 = gmc[1]*s, gm2 = gmc[2]*s, gm3 = gmc[3]*s;
    const f4 s4 = *reinterpret_cast<const f4*>(fbuf + S_OFF + b * Cdim + c0);

    f4 rq;
    {
        float q0 = fminf(fmaxf(rintf(s4[0] * ss_inv), -32768.0f), 32767.0f) * scale_s;
        float q1 = fminf(fmaxf(rintf(s4[1] * ss_inv), -32768.0f), 32767.0f) * scale_s;
        float q2 = fminf(fmaxf(rintf(s4[2] * ss_inv), -32768.0f), 32767.0f) * scale_s;
        float q3 = fminf(fmaxf(rintf(s4[3] * ss_inv), -32768.0f), 32767.0f) * scale_s;
        rq[0] = fminf(fmaxf(rintf((1.0f/q0) * sr_inv), -32768.0f), 32767.0f) * scale_r;
        rq[1] = fminf(fmaxf(rintf((1.0f/q1) * sr_inv), -32768.0f), 32767.0f) * scale_r;
        rq[2] = fminf(fmaxf(rintf((1.0f/q2) * sr_inv), -32768.0f), 32767.0f) * scale_r;
        rq[3] = fminf(fmaxf(rintf((1.0f/q3) * sr_inv), -32768.0f), 32767.0f) * scale_r;
    }

    const size_t base = ((size_t)(b * Jdim + jc * JCHUNK)) * Cdim + c0;
    #pragma unroll 4
    for (int r = 0; r < JCHUNK; ++r) {
        float xq0, xq1, xq2, xq3;
        if (UC) {
            const c4 q = *reinterpret_cast<const c4*>(codes + base + (size_t)r * Cdim);
            xq0 = (float)q[0]*s; xq1 = (float)q[1]*s; xq2 = (float)q[2]*s; xq3 = (float)q[3]*s;
        } else {
            const f4 v = *reinterpret_cast<const f4*>(x + base + (size_t)r * Cdim);
            xq0 = code8f(v[0], sinv)*s; xq1 = code8f(v[1], sinv)*s;
            xq2 = code8f(v[2], sinv)*s; xq3 = code8f(v[3], sinv)*s;
        }
        float e0 = eq_from(xq0, gm0, ssub_inv, ssub) * rq[0];
        float e1 = eq_from(xq1, gm1, ssub_inv, ssub) * rq[1];
        float e2 = eq_from(xq2, gm2, ssub_inv, ssub) * rq[2];
        float e3 = eq_from(xq3, gm3, ssub_inv, ssub) * rq[3];
        f4 o;
        o[0] = fminf(fmaxf(rintf(e0 * so_inv), -128.0f), 127.0f) * scale_out;
        o[1] = fminf(fmaxf(rintf(e1 * so_inv), -128.0f), 127.0f) * scale_out;
        o[2] = fminf(fmaxf(rintf(e2 * so_inv), -128.0f), 127.0f) * scale_out;
        o[3] = fminf(fmaxf(rintf(e3 * so_inv), -128.0f), 127.0f) * scale_out;
        __builtin_nontemporal_store(o, reinterpret_cast<f4*>(out + base + (size_t)r * Cdim));
    }
}

extern "C" void kernel_launch(void* const* d_in, const int* in_sizes, int n_in,
                              void* d_out, int out_size, void* d_ws, size_t ws_size,
                              hipStream_t stream) {
    const float* x     = (const float*)d_in[0];
    const float* scale = (const float*)d_in[1];
    float* out = (float*)d_out;

    // ---- preferred: fused cooperative kernel (4 blocks/CU, no big LDS) ----
    if (ws_size >= WS_NEED) {
        char* wsb = (char*)d_ws;
        const float* xa = x; const float* sa = scale; float* oa = out; char* wa = wsb;
        void* args[4] = {(void*)&xa, (void*)&sa, (void*)&oa, (void*)&wa};
        hipError_t err = hipLaunchCooperativeKernel((const void*)k_fused,
                                                    dim3(FGRID), dim3(FBLK),
                                                    args, 0, stream);
        if (err == hipSuccess) return;
    }

    // ---- fallback: proven round-3 5-kernel path ----
    const bool uc = ws_size >= CODES_BYTES + FB_BYTES + P_BYTES;
    signed char* codes = uc ? (signed char*)d_ws : nullptr;
    float* fbuf = uc ? (float*)((char*)d_ws + CODES_BYTES) : (float*)d_ws;
    signed char* pmax = (signed char*)((char*)fbuf + FB_BYTES);
    signed char* pmin = pmax + PSIZE;

    if (uc) {
        k_pass1<true ><<<Bdim * NJC, 256, 0, stream>>>(x, scale, fbuf, codes, pmax, pmin);
        k_reduce1<<<256, 256, 0, stream>>>(scale, fbuf, pmax, pmin);
        k_pass2<true ><<<Bdim * NJC, 256, 0, stream>>>(x, codes, scale, fbuf);
        k_reduce2<<<256, 256, 0, stream>>>(fbuf);
        k_pass3<true ><<<Bdim * NJC, 256, 0, stream>>>(x, codes, scale, fbuf, out);
    } else {
        k_pass1<false><<<Bdim * NJC, 256, 0, stream>>>(x, scale, fbuf, codes, pmax, pmin);
        k_reduce1<<<256, 256, 0, stream>>>(scale, fbuf, pmax, pmin);
        k_pass2<false><<<Bdim * NJC, 256, 0, stream>>>(x, codes, scale, fbuf);
        k_reduce2<<<256, 256, 0, stream>>>(fbuf);
        k_pass3<false><<<Bdim * NJC, 256, 0, stream>>>(x, codes, scale, fbuf, out);
    }
}

// Round 8
// 193.948 us; speedup vs baseline: 3.1294x; 3.1294x over previous
//
#include <hip/hip_runtime.h>
#include <hip/hip_cooperative_groups.h>
#include <math.h>

namespace cgx = cooperative_groups;

// Quantized softmax over axis 1 of x(8, 4096, 1024) fp32.
// Groups: (b, c) column, 8192 groups of 4096 elements (stride 1024 floats).
//
// Round-8: fused cooperative kernel, 512 blocks x 512 thr = 2 blocks/CU.
//   - Codes slab in LDS: 4096 rows x 16 cols = 64 KiB/block (R5 architecture,
//     R6 geometry -- both proven correct).
//   - __launch_bounds__(512,4): VGPR cap 128. R7 lesson: forcing min-waves=8
//     gave VGPR=28 -> serialized loads -> 0.52 TB/s. Occupancy without
//     registers is worthless.
//   - Phase A: explicit A/B 4-deep load batches (static register names) to
//     force >=4 f4 loads in flight per thread.
//   - No LDS LUT (R6 lesson: data-dependent gathers = 4.5M bank conflicts).
//   - 2 grid syncs; cross-block scalars via per-block ws arrays + redundant
//     re-reduction. No float atomics, deterministic.
// Fallback: proven round-3 5-kernel path (101 us).

typedef float       f4 __attribute__((ext_vector_type(4)));
typedef signed char c4 __attribute__((ext_vector_type(4)));

static constexpr int Bdim = 8;
static constexpr int Jdim = 4096;
static constexpr int Cdim = 1024;
static constexpr int NG   = Bdim * Cdim;

// ---- fused geometry ----
static constexpr int CT    = 16;            // columns per block
static constexpr int NCT   = Cdim / CT;     // 64
static constexpr int FGRID = Bdim * NCT;    // 512 blocks = 2 per CU
static constexpr int FBLK  = 512;           // 8 waves
static constexpr int KROWS = 32;            // row-steps per thread
static constexpr int RSTEP = 128;           // row stride between steps

__device__ __forceinline__ float code8f(float x, float sinv) {
    // int8 code as float; rintf = round-half-even matches jnp.round
    return fminf(fmaxf(rintf(x * sinv), -128.0f), 127.0f);
}
// e_q = fq16(exp(fq16(clip(xq - gmax, -12, 0)))); scale_e = 1/32767 exactly
// (group-max element has sub==0 -> e==1 -> absmax(e)==1).
__device__ __forceinline__ float eq_from(float xq, float gmv, float ssub_inv, float ssub) {
    float sub = fminf(fmaxf(xq - gmv, -12.0f), 0.0f);
    float q   = rintf(sub * ssub_inv);
    float e   = __expf(q * ssub);
    return rintf(e * 32767.0f) * (1.0f / 32767.0f);
}
__device__ __forceinline__ f4 shfl_xor4(f4 v, int off) {
    f4 r; r[0] = __shfl_xor(v[0], off); r[1] = __shfl_xor(v[1], off);
    r[2] = __shfl_xor(v[2], off); r[3] = __shfl_xor(v[3], off); return r;
}
__device__ __forceinline__ f4 fmax4v(f4 a, f4 b) {
    f4 r; r[0]=fmaxf(a[0],b[0]); r[1]=fmaxf(a[1],b[1]);
    r[2]=fmaxf(a[2],b[2]); r[3]=fmaxf(a[3],b[3]); return r;
}
__device__ __forceinline__ f4 fmin4v(f4 a, f4 b) {
    f4 r; r[0]=fminf(a[0],b[0]); r[1]=fminf(a[1],b[1]);
    r[2]=fminf(a[2],b[2]); r[3]=fminf(a[3],b[3]); return r;
}
__device__ __forceinline__ f4 add4v(f4 a, f4 b) {
    f4 r; r[0]=a[0]+b[0]; r[1]=a[1]+b[1]; r[2]=a[2]+b[2]; r[3]=a[3]+b[3]; return r;
}

__global__ __launch_bounds__(FBLK, 4) void k_fused(const float* __restrict__ x,
                                                   const float* __restrict__ scale,
                                                   float* __restrict__ out,
                                                   float* __restrict__ wsf) {
    const int bid   = blockIdx.x;
    const int b     = bid >> 6;          // batch 0..7
    const int ctile = bid & 63;          // 16-col tile
    const int t     = threadIdx.x;
    const int cgp   = t & 3;             // col group: 4 cols
    const int rg    = t >> 2;            // 0..127 row slot
    const int w     = t >> 6;            // wave 0..7
    const int l     = t & 63;            // lane
    const float s    = scale[0];
    const float sinv = 1.0f / s;

    float* dblk  = wsf;                  // [512] per-block max clip(sub) range
    float* smaxb = wsf + 512;            // [512] per-block max group-sum
    float* sminb = wsf + 1024;           // [512] per-block min group-sum

    __shared__ signed char lcode[Jdim * CT];   // 64 KiB code slab
    __shared__ f4 lA[8][4], lB[8][4];
    __shared__ float gmcolv[CT];         // per-col gmax VALUE (= code*s)
    __shared__ f4 scol4[4];              // per-colgroup group sums
    __shared__ float sred[8], sred2[8];
    __shared__ float bc[3];

    const size_t gbase = ((size_t)(b * Jdim + rg)) * Cdim + (size_t)(ctile * CT + cgp * 4);
    const float* xp = x + gbase;
    float* op = out + gbase;
    const int lbase = rg * CT + cgp * 4; // byte offset in slab
    signed char* lc = lcode + lbase;

    // ---------- Phase A: read x (A/B 4-deep batches), quantize -> LDS, col max/min
    f4 vmax = {-1e30f, -1e30f, -1e30f, -1e30f};
    f4 vmin = { 1e30f,  1e30f,  1e30f,  1e30f};

    auto LD = [&](int k) -> f4 {
        return __builtin_nontemporal_load(
            reinterpret_cast<const f4*>(xp + (size_t)k * (RSTEP * Cdim)));
    };
    auto PROC = [&](f4 v, int k) {
        f4 q;
        q[0] = code8f(v[0], sinv); q[1] = code8f(v[1], sinv);
        q[2] = code8f(v[2], sinv); q[3] = code8f(v[3], sinv);
        vmax = fmax4v(vmax, q); vmin = fmin4v(vmin, q);
        *reinterpret_cast<c4*>(lc + k * (RSTEP * CT)) =
            (c4){(signed char)(int)q[0], (signed char)(int)q[1],
                 (signed char)(int)q[2], (signed char)(int)q[3]};
    };

    f4 va0 = LD(0), va1 = LD(1), va2 = LD(2), va3 = LD(3);
#pragma unroll
    for (int kb = 0; kb < 4; ++kb) {
        const int k0 = kb * 8;
        f4 vb0 = LD(k0 + 4), vb1 = LD(k0 + 5), vb2 = LD(k0 + 6), vb3 = LD(k0 + 7);
        PROC(va0, k0); PROC(va1, k0 + 1); PROC(va2, k0 + 2); PROC(va3, k0 + 3);
        if (kb < 3) {
            va0 = LD(k0 + 8); va1 = LD(k0 + 9); va2 = LD(k0 + 10); va3 = LD(k0 + 11);
        }
        PROC(vb0, k0 + 4); PROC(vb1, k0 + 5); PROC(vb2, k0 + 6); PROC(vb3, k0 + 7);
    }

    // wave reduce over row bits (lane bits 2..5); lanes sharing cgp combine
#pragma unroll
    for (int off = 4; off < 64; off <<= 1) {
        vmax = fmax4v(vmax, shfl_xor4(vmax, off));
        vmin = fmin4v(vmin, shfl_xor4(vmin, off));
    }
    if (l < 4) { lA[w][l] = vmax; lB[w][l] = vmin; }
    __syncthreads();
    if (w == 0 && l < 32) {
        const int wi = l >> 2, cg = l & 3;
        f4 m = lA[wi][cg], n = lB[wi][cg];
#pragma unroll
        for (int off = 4; off < 32; off <<= 1) {
            m = fmax4v(m, shfl_xor4(m, off));
            n = fmin4v(n, shfl_xor4(n, off));
        }
        if (l < 4) {                     // lanes 0..3: final per-colgroup
            float d = -1e30f;
#pragma unroll
            for (int i = 0; i < 4; ++i) {
                gmcolv[l * 4 + i] = m[i] * s;                 // == ref max(xq)
                d = fmaxf(d, fminf(12.0f, m[i] * s - n[i] * s));
            }
            d = fmaxf(d, __shfl_xor(d, 1));
            d = fmaxf(d, __shfl_xor(d, 2));
            if (l == 0) dblk[bid] = d;
        }
    }
    cgx::this_grid().sync();

    // ---------- Phase B: global amax_sub; e_q column sums
    {
        float v = dblk[t];               // 512 entries, one per thread
#pragma unroll
        for (int off = 1; off < 64; off <<= 1) v = fmaxf(v, __shfl_xor(v, off));
        if (l == 0) sred[w] = v;
    }
    __syncthreads();
    if (t < 8) {
        float v = sred[t];
        v = fmaxf(v, __shfl_xor(v, 1));
        v = fmaxf(v, __shfl_xor(v, 2));
        v = fmaxf(v, __shfl_xor(v, 4));
        if (t == 0) bc[0] = v;
    }
    __syncthreads();
    const float amax = fmaxf(bc[0], 1e-9f);
    const float ssub = amax / 32767.0f;
    const float ssub_inv = 1.0f / ssub;
    const f4 gm = {gmcolv[cgp * 4 + 0], gmcolv[cgp * 4 + 1],
                   gmcolv[cgp * 4 + 2], gmcolv[cgp * 4 + 3]};

    f4 acc = {0.f, 0.f, 0.f, 0.f};
#pragma unroll
    for (int k = 0; k < KROWS; ++k) {
        const c4 q = *reinterpret_cast<const c4*>(lc + k * (RSTEP * CT));
        acc[0] += eq_from((float)q[0] * s, gm[0], ssub_inv, ssub);
        acc[1] += eq_from((float)q[1] * s, gm[1], ssub_inv, ssub);
        acc[2] += eq_from((float)q[2] * s, gm[2], ssub_inv, ssub);
        acc[3] += eq_from((float)q[3] * s, gm[3], ssub_inv, ssub);
    }
#pragma unroll
    for (int off = 4; off < 64; off <<= 1) acc = add4v(acc, shfl_xor4(acc, off));
    if (l < 4) lA[w][l] = acc;
    __syncthreads();
    if (w == 0 && l < 32) {
        const int wi = l >> 2, cg = l & 3;
        f4 tsum = lA[wi][cg];
#pragma unroll
        for (int off = 4; off < 32; off <<= 1) tsum = add4v(tsum, shfl_xor4(tsum, off));
        if (l < 4) {
            scol4[l] = tsum;
            float mx = fmaxf(fmaxf(tsum[0], tsum[1]), fmaxf(tsum[2], tsum[3]));
            float mn = fminf(fminf(tsum[0], tsum[1]), fminf(tsum[2], tsum[3]));
            mx = fmaxf(mx, __shfl_xor(mx, 1)); mn = fminf(mn, __shfl_xor(mn, 1));
            mx = fmaxf(mx, __shfl_xor(mx, 2)); mn = fminf(mn, __shfl_xor(mn, 2));
            if (l == 0) { smaxb[bid] = mx; sminb[bid] = mn; }
        }
    }
    cgx::this_grid().sync();

    // ---------- Phase C: derive scales; out = fq8(e_q * r_q)
    {
        float vmx = smaxb[t], vmn = sminb[t];
#pragma unroll
        for (int off = 1; off < 64; off <<= 1) {
            vmx = fmaxf(vmx, __shfl_xor(vmx, off));
            vmn = fminf(vmn, __shfl_xor(vmn, off));
        }
        if (l == 0) { sred[w] = vmx; sred2[w] = vmn; }
    }
    __syncthreads();
    if (t < 8) {
        float vmx = sred[t], vmn = sred2[t];
        vmx = fmaxf(vmx, __shfl_xor(vmx, 1)); vmn = fminf(vmn, __shfl_xor(vmn, 1));
        vmx = fmaxf(vmx, __shfl_xor(vmx, 2)); vmn = fminf(vmn, __shfl_xor(vmn, 2));
        vmx = fmaxf(vmx, __shfl_xor(vmx, 4)); vmn = fminf(vmn, __shfl_xor(vmn, 4));
        if (t == 0) { bc[1] = vmx; bc[2] = vmn; }
    }
    __syncthreads();
    const float max_s = bc[1], min_s = bc[2];
    // fq monotone: min s_q = fq(min s); max r = 1/min s_q; max r_q = fq(max r)
    const float scale_s = fmaxf(max_s, 1e-9f) / 32767.0f;
    const float ss_inv  = 1.0f / scale_s;
    const float minsq   = fminf(fmaxf(rintf(min_s * ss_inv), -32768.0f), 32767.0f) * scale_s;
    const float maxr    = 1.0f / minsq;
    const float scale_r = fmaxf(maxr, 1e-9f) / 32767.0f;
    const float sr_inv  = 1.0f / scale_r;
    const float maxrq   = fminf(fmaxf(rintf(maxr * sr_inv), -32768.0f), 32767.0f) * scale_r;
    const float scale_out = fmaxf(maxrq, 1e-9f) / 127.0f;
    const float so_inv  = 1.0f / scale_out;

    const f4 sc = scol4[cgp];
    f4 rq;
#pragma unroll
    for (int i = 0; i < 4; ++i) {
        float qv = fminf(fmaxf(rintf(sc[i] * ss_inv), -32768.0f), 32767.0f) * scale_s;
        rq[i] = fminf(fmaxf(rintf((1.0f / qv) * sr_inv), -32768.0f), 32767.0f) * scale_r;
    }

#pragma unroll
    for (int k = 0; k < KROWS; ++k) {
        const c4 q = *reinterpret_cast<const c4*>(lc + k * (RSTEP * CT));
        const float e0 = eq_from((float)q[0] * s, gm[0], ssub_inv, ssub) * rq[0];
        const float e1 = eq_from((float)q[1] * s, gm[1], ssub_inv, ssub) * rq[1];
        const float e2 = eq_from((float)q[2] * s, gm[2], ssub_inv, ssub) * rq[2];
        const float e3 = eq_from((float)q[3] * s, gm[3], ssub_inv, ssub) * rq[3];
        f4 o;
        o[0] = fminf(fmaxf(rintf(e0 * so_inv), -128.0f), 127.0f) * scale_out;
        o[1] = fminf(fmaxf(rintf(e1 * so_inv), -128.0f), 127.0f) * scale_out;
        o[2] = fminf(fmaxf(rintf(e2 * so_inv), -128.0f), 127.0f) * scale_out;
        o[3] = fminf(fmaxf(rintf(e3 * so_inv), -128.0f), 127.0f) * scale_out;
        __builtin_nontemporal_store(o,
            reinterpret_cast<f4*>(op + (size_t)k * (RSTEP * Cdim)));
    }
}

// ======================= round-3 fallback path (proven, 101 us) =======================
static constexpr int JCHUNK = 16;
static constexpr int NJC = Jdim / JCHUNK;
static constexpr int PSIZE = Bdim * NJC * Cdim;

static constexpr int SC_OFF   = 0;
static constexpr int GMAX_OFF = 16;
static constexpr int S_OFF    = GMAX_OFF + NG;
static constexpr int PS_OFF   = S_OFF + NG;
static constexpr size_t FB_BYTES    = ((size_t)PS_OFF + PSIZE) * 4;
static constexpr size_t CODES_BYTES = (size_t)Bdim * Jdim * Cdim;
static constexpr size_t P_BYTES     = 2 * (size_t)PSIZE;

template <bool WC>
__global__ __launch_bounds__(256) void k_pass1(const float* __restrict__ x,
                                               const float* __restrict__ scale,
                                               float* __restrict__ fbuf,
                                               signed char* __restrict__ codes,
                                               signed char* __restrict__ pmax,
                                               signed char* __restrict__ pmin) {
    if (blockIdx.x == 0 && threadIdx.x == 0) {
        fbuf[SC_OFF + 0] = 0.0f;
        fbuf[SC_OFF + 1] = 0.0f;
        fbuf[SC_OFF + 2] = __int_as_float(0x7f800000);
    }
    const int b  = blockIdx.x / NJC;
    const int jc = blockIdx.x % NJC;
    const int c0 = threadIdx.x * 4;
    const float sinv = 1.0f / scale[0];
    const size_t base = ((size_t)(b * Jdim + jc * JCHUNK)) * Cdim + c0;

    f4 vmax = {-1e30f, -1e30f, -1e30f, -1e30f};
    f4 vmin = { 1e30f,  1e30f,  1e30f,  1e30f};
    #pragma unroll 4
    for (int r = 0; r < JCHUNK; ++r) {
        const f4 v = __builtin_nontemporal_load(
            reinterpret_cast<const f4*>(x + base + (size_t)r * Cdim));
        f4 q;
        q[0] = code8f(v[0], sinv); q[1] = code8f(v[1], sinv);
        q[2] = code8f(v[2], sinv); q[3] = code8f(v[3], sinv);
        vmax = fmax4v(vmax, q); vmin = fmin4v(vmin, q);
        if (WC) {
            c4 pk = {(signed char)(int)q[0], (signed char)(int)q[1],
                     (signed char)(int)q[2], (signed char)(int)q[3]};
            *reinterpret_cast<c4*>(codes + base + (size_t)r * Cdim) = pk;
        }
    }
    const size_t pidx = ((size_t)(b * NJC + jc)) * Cdim + c0;
    c4 mx = {(signed char)(int)vmax[0], (signed char)(int)vmax[1],
             (signed char)(int)vmax[2], (signed char)(int)vmax[3]};
    c4 mn = {(signed char)(int)vmin[0], (signed char)(int)vmin[1],
             (signed char)(int)vmin[2], (signed char)(int)vmin[3]};
    *reinterpret_cast<c4*>(pmax + pidx) = mx;
    *reinterpret_cast<c4*>(pmin + pidx) = mn;
}

__global__ __launch_bounds__(256) void k_reduce1(const float* __restrict__ scale,
                                                 float* __restrict__ fbuf,
                                                 const signed char* __restrict__ pmax,
                                                 const signed char* __restrict__ pmin) {
    const int b   = blockIdx.x / 32;
    const int ct  = blockIdx.x % 32;
    const int ci  = threadIdx.x & 31;
    const int sub = threadIdx.x >> 5;
    const int c   = ct * 32 + ci;

    int mx = -128, mn = 127;
    for (int jc = sub; jc < NJC; jc += 8) {
        const size_t idx = ((size_t)(b * NJC + jc)) * Cdim + c;
        mx = max(mx, (int)pmax[idx]);
        mn = min(mn, (int)pmin[idx]);
    }
    __shared__ int smx[8][32], smn[8][32];
    smx[sub][ci] = mx; smn[sub][ci] = mn;
    __syncthreads();
    for (int off = 4; off; off >>= 1) {
        if (sub < off) {
            smx[sub][ci] = max(smx[sub][ci], smx[sub + off][ci]);
            smn[sub][ci] = min(smn[sub][ci], smn[sub + off][ci]);
        }
        __syncthreads();
    }
    __shared__ float sd[32];
    if (sub == 0) {
        const float s = scale[0];
        fbuf[GMAX_OFF + b * Cdim + c] = (float)smx[0][ci];
        sd[ci] = fminf(12.0f, (float)smx[0][ci] * s - (float)smn[0][ci] * s);
    }
    __syncthreads();
    if (threadIdx.x == 0) {
        float m = sd[0];
        #pragma unroll
        for (int i = 1; i < 32; ++i) m = fmaxf(m, sd[i]);
        atomicMax(reinterpret_cast<unsigned int*>(fbuf + SC_OFF + 0), __float_as_uint(m));
    }
}

template <bool UC>
__global__ __launch_bounds__(256) void k_pass2(const float* __restrict__ x,
                                               const signed char* __restrict__ codes,
                                               const float* __restrict__ scale,
                                               float* __restrict__ fbuf) {
    const int b  = blockIdx.x / NJC;
    const int jc = blockIdx.x % NJC;
    const int c0 = threadIdx.x * 4;
    const float s = scale[0];
    const float sinv = 1.0f / s;
    const float amax = fmaxf(fbuf[SC_OFF + 0], 1e-9f);
    const float ssub = amax / 32767.0f;
    const float ssub_inv = 1.0f / ssub;
    const f4 gmc = *reinterpret_cast<const f4*>(fbuf + GMAX_OFF + b * Cdim + c0);
    const float gm0 = gmc[0]*s, gm1 = gmc[1]*s, gm2 = gmc[2]*s, gm3 = gmc[3]*s;
    const size_t base = ((size_t)(b * Jdim + jc * JCHUNK)) * Cdim + c0;

    float a0 = 0.f, a1 = 0.f, a2 = 0.f, a3 = 0.f;
    #pragma unroll 4
    for (int r = 0; r < JCHUNK; ++r) {
        float xq0, xq1, xq2, xq3;
        if (UC) {
            const c4 q = *reinterpret_cast<const c4*>(codes + base + (size_t)r * Cdim);
            xq0 = (float)q[0]*s; xq1 = (float)q[1]*s; xq2 = (float)q[2]*s; xq3 = (float)q[3]*s;
        } else {
            const f4 v = *reinterpret_cast<const f4*>(x + base + (size_t)r * Cdim);
            xq0 = code8f(v[0], sinv)*s; xq1 = code8f(v[1], sinv)*s;
            xq2 = code8f(v[2], sinv)*s; xq3 = code8f(v[3], sinv)*s;
        }
        a0 += eq_from(xq0, gm0, ssub_inv, ssub);
        a1 += eq_from(xq1, gm1, ssub_inv, ssub);
        a2 += eq_from(xq2, gm2, ssub_inv, ssub);
        a3 += eq_from(xq3, gm3, ssub_inv, ssub);
    }
    f4 acc = {a0, a1, a2, a3};
    *reinterpret_cast<f4*>(fbuf + PS_OFF + ((size_t)(b * NJC + jc)) * Cdim + c0) = acc;
}

__global__ __launch_bounds__(256) void k_reduce2(float* __restrict__ fbuf) {
    const int b   = blockIdx.x / 32;
    const int ct  = blockIdx.x % 32;
    const int ci  = threadIdx.x & 31;
    const int sub = threadIdx.x >> 5;
    const int c   = ct * 32 + ci;

    float p = 0.0f;
    for (int jc = sub; jc < NJC; jc += 8)
        p += fbuf[PS_OFF + ((size_t)(b * NJC + jc)) * Cdim + c];
    __shared__ float sp[8][32];
    sp[sub][ci] = p;
    __syncthreads();
    for (int off = 4; off; off >>= 1) {
        if (sub < off) sp[sub][ci] += sp[sub + off][ci];
        __syncthreads();
    }
    __shared__ float smx[32], smn[32];
    if (sub == 0) {
        const float tv = sp[0][ci];
        fbuf[S_OFF + b * Cdim + c] = tv;
        smx[ci] = tv; smn[ci] = tv;
    }
    __syncthreads();
    if (threadIdx.x == 0) {
        float mx = smx[0], mn = smn[0];
        #pragma unroll
        for (int i = 1; i < 32; ++i) { mx = fmaxf(mx, smx[i]); mn = fminf(mn, smn[i]); }
        atomicMax(reinterpret_cast<unsigned int*>(fbuf + SC_OFF + 1), __float_as_uint(mx));
        atomicMin(reinterpret_cast<unsigned int*>(fbuf + SC_OFF + 2), __float_as_uint(mn));
    }
}

template <bool UC>
__global__ __launch_bounds__(256) void k_pass3(const float* __restrict__ x,
                                               const signed char* __restrict__ codes,
                                               const float* __restrict__ scale,
                                               const float* __restrict__ fbuf,
                                               float* __restrict__ out) {
    const int b  = blockIdx.x / NJC;
    const int jc = blockIdx.x % NJC;
    const int c0 = threadIdx.x * 4;
    const float s = scale[0];
    const float sinv = 1.0f / s;

    const float amax = fmaxf(fbuf[SC_OFF + 0], 1e-9f);
    const float ssub = amax / 32767.0f;
    const float ssub_inv = 1.0f / ssub;

    const float max_s = fbuf[SC_OFF + 1];
    const float min_s = fbuf[SC_OFF + 2];
    const float scale_s = fmaxf(max_s, 1e-9f) / 32767.0f;
    const float ss_inv = 1.0f / scale_s;
    const float minsq = fminf(fmaxf(rintf(min_s * ss_inv), -32768.0f), 32767.0f) * scale_s;
    const float maxr  = 1.0f / minsq;
    const float scale_r = fmaxf(maxr, 1e-9f) / 32767.0f;
    const float sr_inv  = 1.0f / scale_r;
    const float maxrq = fminf(fmaxf(rintf(maxr * sr_inv), -32768.0f), 32767.0f) * scale_r;
    const float scale_out = fmaxf(maxrq, 1e-9f) / 127.0f;
    const float so_inv = 1.0f / scale_out;

    const f4 gmc = *reinterpret_cast<const f4*>(fbuf + GMAX_OFF + b * Cdim + c0);
    const float gm0 = gmc[0]*s, gm1 = gmc[1]*s, gm2 = gmc[2]*s, gm3 = gmc[3]*s;
    const f4 s4 = *reinterpret_cast<const f4*>(fbuf + S_OFF + b * Cdim + c0);

    f4 rq;
    {
        float q0 = fminf(fmaxf(rintf(s4[0] * ss_inv), -32768.0f), 32767.0f) * scale_s;
        float q1 = fminf(fmaxf(rintf(s4[1] * ss_inv), -32768.0f), 32767.0f) * scale_s;
        float q2 = fminf(fmaxf(rintf(s4[2] * ss_inv), -32768.0f), 32767.0f) * scale_s;
        float q3 = fminf(fmaxf(rintf(s4[3] * ss_inv), -32768.0f), 32767.0f) * scale_s;
        rq[0] = fminf(fmaxf(rintf((1.0f/q0) * sr_inv), -32768.0f), 32767.0f) * scale_r;
        rq[1] = fminf(fmaxf(rintf((1.0f/q1) * sr_inv), -32768.0f), 32767.0f) * scale_r;
        rq[2] = fminf(fmaxf(rintf((1.0f/q2) * sr_inv), -32768.0f), 32767.0f) * scale_r;
        rq[3] = fminf(fmaxf(rintf((1.0f/q3) * sr_inv), -32768.0f), 32767.0f) * scale_r;
    }

    const size_t base = ((size_t)(b * Jdim + jc * JCHUNK)) * Cdim + c0;
    #pragma unroll 4
    for (int r = 0; r < JCHUNK; ++r) {
        float xq0, xq1, xq2, xq3;
        if (UC) {
            const c4 q = *reinterpret_cast<const c4*>(codes + base + (size_t)r * Cdim);
            xq0 = (float)q[0]*s; xq1 = (float)q[1]*s; xq2 = (float)q[2]*s; xq3 = (float)q[3]*s;
        } else {
            const f4 v = *reinterpret_cast<const f4*>(x + base + (size_t)r * Cdim);
            xq0 = code8f(v[0], sinv)*s; xq1 = code8f(v[1], sinv)*s;
            xq2 = code8f(v[2], sinv)*s; xq3 = code8f(v[3], sinv)*s;
        }
        float e0 = eq_from(xq0, gm0, ssub_inv, ssub) * rq[0];
        float e1 = eq_from(xq1, gm1, ssub_inv, ssub) * rq[1];
        float e2 = eq_from(xq2, gm2, ssub_inv, ssub) * rq[2];
        float e3 = eq_from(xq3, gm3, ssub_inv, ssub) * rq[3];
        f4 o;
        o[0] = fminf(fmaxf(rintf(e0 * so_inv), -128.0f), 127.0f) * scale_out;
        o[1] = fminf(fmaxf(rintf(e1 * so_inv), -128.0f), 127.0f) * scale_out;
        o[2] = fminf(fmaxf(rintf(e2 * so_inv), -128.0f), 127.0f) * scale_out;
        o[3] = fminf(fmaxf(rintf(e3 * so_inv), -128.0f), 127.0f) * scale_out;
        __builtin_nontemporal_store(o, reinterpret_cast<f4*>(out + base + (size_t)r * Cdim));
    }
}

extern "C" void kernel_launch(void* const* d_in, const int* in_sizes, int n_in,
                              void* d_out, int out_size, void* d_ws, size_t ws_size,
                              hipStream_t stream) {
    const float* x     = (const float*)d_in[0];
    const float* scale = (const float*)d_in[1];
    float* out = (float*)d_out;

    // ---- preferred: fused cooperative kernel (2 blocks/CU, LDS slab) ----
    {
        float* wsf = (float*)d_ws;   // needs 1536 floats
        const float* xa = x; const float* sa = scale; float* oa = out; float* wa = wsf;
        void* args[4] = {(void*)&xa, (void*)&sa, (void*)&oa, (void*)&wa};
        hipError_t err = hipLaunchCooperativeKernel((const void*)k_fused,
                                                    dim3(FGRID), dim3(FBLK),
                                                    args, 0, stream);
        if (err == hipSuccess) return;
    }

    // ---- fallback: proven round-3 5-kernel path ----
    const bool uc = ws_size >= CODES_BYTES + FB_BYTES + P_BYTES;
    signed char* codes = uc ? (signed char*)d_ws : nullptr;
    float* fbuf = uc ? (float*)((char*)d_ws + CODES_BYTES) : (float*)d_ws;
    signed char* pmax = (signed char*)((char*)fbuf + FB_BYTES);
    signed char* pmin = pmax + PSIZE;

    if (uc) {
        k_pass1<true ><<<Bdim * NJC, 256, 0, stream>>>(x, scale, fbuf, codes, pmax, pmin);
        k_reduce1<<<256, 256, 0, stream>>>(scale, fbuf, pmax, pmin);
        k_pass2<true ><<<Bdim * NJC, 256, 0, stream>>>(x, codes, scale, fbuf);
        k_reduce2<<<256, 256, 0, stream>>>(fbuf);
        k_pass3<true ><<<Bdim * NJC, 256, 0, stream>>>(x, codes, scale, fbuf, out);
    } else {
        k_pass1<false><<<Bdim * NJC, 256, 0, stream>>>(x, scale, fbuf, codes, pmax, pmin);
        k_reduce1<<<256, 256, 0, stream>>>(scale, fbuf, pmax, pmin);
        k_pass2<false><<<Bdim * NJC, 256, 0, stream>>>(x, codes, scale, fbuf);
        k_reduce2<<<256, 256, 0, stream>>>(fbuf);
        k_pass3<false><<<Bdim * NJC, 256, 0, stream>>>(x, codes, scale, fbuf, out);
    }
}

// Round 9
// 112.687 us; speedup vs baseline: 5.3861x; 1.7211x over previous
//
#include <hip/hip_runtime.h>
#include <math.h>

// Quantized softmax over axis 1 of x(8, 4096, 1024) fp32.
// Groups: (b, c) column, 8192 groups of 4096 elements (stride 1024 floats).
//
// Round-9: 4 plain kernels (cooperative path abandoned after R4-R8: grid
// syncs + column-slab HBM streaming consistently lost to row-chunk passes).
//   K1 p1: read x (NT, 8-deep), quantize -> codes (32MB, plain stores -> L2)
//          + per-(jc,g) max/min code partials ([jc][g] layout, coalesced).
//   K2 r1: per-group gmax code -> gmv[g]; global amax_sub via atomicMax.
//   K3 p2: column-slab blocks read L2/L3-resident codes, compute FULL group
//          sums (R8 phase-B tree, proven) -> sarr[g]; global max/min s via
//          2 atomics. Kills the old psum+reduce2 round-trip.
//   K4 p3: read codes (row-chunk, L2-warm) + scalars -> out (NT stores).
// All atomics are max/min on uint (order-independent -> deterministic).
// Scalars re-initialized by K1 block 0 every call (no stale ws state).

typedef float       f4 __attribute__((ext_vector_type(4)));
typedef signed char c4 __attribute__((ext_vector_type(4)));

static constexpr int Bdim = 8;
static constexpr int Jdim = 4096;
static constexpr int Cdim = 1024;
static constexpr int NG   = Bdim * Cdim;          // 8192 groups

static constexpr int JC1   = 16;                  // rows per P1/P3 block
static constexpr int NJC   = Jdim / JC1;          // 256
static constexpr int GRID1 = Bdim * NJC;          // 2048

// ws byte offsets
static constexpr size_t SC_B    = 0;              // f32[3] scalars
static constexpr size_t GMV_B   = 1024;           // f32[8192] group max CODE
static constexpr size_t SARR_B  = 36864;          // f32[8192] group sums
static constexpr size_t PMAX_B  = 131072;         // i8[256][8192]
static constexpr size_t PMIN_B  = PMAX_B + 2097152;
static constexpr size_t CODES_B = 8388608;        // i8[8][4096][1024] = 32 MB
static constexpr size_t WS_FULL = CODES_B + 33554432;   // 40 MB
static constexpr size_t WS_MIN  = PMIN_B + 2097152;     // ~6.3 MB (no-codes path)

__device__ __forceinline__ float code8f(float x, float sinv) {
    // int8 code as float; rintf = round-half-even matches jnp.round
    return fminf(fmaxf(rintf(x * sinv), -128.0f), 127.0f);
}
// e_q = fq16(exp(fq16(clip(xq - gmax, -12, 0)))); scale_e = 1/32767 exactly
// (group-max element has sub==0 -> e==1 -> absmax(e)==1).
__device__ __forceinline__ float eq_from(float xq, float gmv, float ssub_inv, float ssub) {
    float sub = fminf(fmaxf(xq - gmv, -12.0f), 0.0f);
    float q   = rintf(sub * ssub_inv);
    float e   = __expf(q * ssub);
    return rintf(e * 32767.0f) * (1.0f / 32767.0f);
}
__device__ __forceinline__ f4 shfl_xor4(f4 v, int off) {
    f4 r; r[0] = __shfl_xor(v[0], off); r[1] = __shfl_xor(v[1], off);
    r[2] = __shfl_xor(v[2], off); r[3] = __shfl_xor(v[3], off); return r;
}
__device__ __forceinline__ f4 fmax4v(f4 a, f4 b) {
    f4 r; r[0]=fmaxf(a[0],b[0]); r[1]=fmaxf(a[1],b[1]);
    r[2]=fmaxf(a[2],b[2]); r[3]=fmaxf(a[3],b[3]); return r;
}
__device__ __forceinline__ f4 fmin4v(f4 a, f4 b) {
    f4 r; r[0]=fminf(a[0],b[0]); r[1]=fminf(a[1],b[1]);
    r[2]=fminf(a[2],b[2]); r[3]=fminf(a[3],b[3]); return r;
}
__device__ __forceinline__ f4 add4v(f4 a, f4 b) {
    f4 r; r[0]=a[0]+b[0]; r[1]=a[1]+b[1]; r[2]=a[2]+b[2]; r[3]=a[3]+b[3]; return r;
}

// ---------------- K1: quantize pass ----------------
template <bool WC>
__global__ __launch_bounds__(256) void k_p1(const float* __restrict__ x,
                                            const float* __restrict__ scale,
                                            char* __restrict__ ws) {
    float* sc = (float*)(ws + SC_B);
    if (blockIdx.x == 0 && threadIdx.x == 0) {
        sc[0] = 0.0f;                        // amax_sub (atomicMax, >=0)
        sc[1] = 0.0f;                        // max_s    (atomicMax, >0)
        sc[2] = __int_as_float(0x7f800000);  // min_s = +inf (atomicMin)
    }
    const int b  = blockIdx.x / NJC;
    const int jc = blockIdx.x % NJC;
    const int c0 = threadIdx.x * 4;
    const float sinv = 1.0f / scale[0];
    const size_t base = ((size_t)(b * Jdim + jc * JC1)) * Cdim + c0;
    signed char* codes = (signed char*)(ws + CODES_B);

    f4 vmax = {-1e30f, -1e30f, -1e30f, -1e30f};
    f4 vmin = { 1e30f,  1e30f,  1e30f,  1e30f};
#pragma unroll
    for (int r0 = 0; r0 < JC1; r0 += 8) {
        f4 v[8];
#pragma unroll
        for (int j = 0; j < 8; ++j)                 // 8 loads in flight
            v[j] = __builtin_nontemporal_load(
                reinterpret_cast<const f4*>(x + base + (size_t)(r0 + j) * Cdim));
#pragma unroll
        for (int j = 0; j < 8; ++j) {
            f4 q;
            q[0] = code8f(v[j][0], sinv); q[1] = code8f(v[j][1], sinv);
            q[2] = code8f(v[j][2], sinv); q[3] = code8f(v[j][3], sinv);
            vmax = fmax4v(vmax, q); vmin = fmin4v(vmin, q);
            if (WC)
                *reinterpret_cast<c4*>(codes + base + (size_t)(r0 + j) * Cdim) =
                    (c4){(signed char)(int)q[0], (signed char)(int)q[1],
                         (signed char)(int)q[2], (signed char)(int)q[3]};
        }
    }
    // partials in [jc][g] layout (g = b*1024 + c) -> coalesced in K2
    const size_t pidx = (size_t)jc * NG + b * Cdim + c0;
    *reinterpret_cast<c4*>(ws + PMAX_B + pidx) =
        (c4){(signed char)(int)vmax[0], (signed char)(int)vmax[1],
             (signed char)(int)vmax[2], (signed char)(int)vmax[3]};
    *reinterpret_cast<c4*>(ws + PMIN_B + pidx) =
        (c4){(signed char)(int)vmin[0], (signed char)(int)vmin[1],
             (signed char)(int)vmin[2], (signed char)(int)vmin[3]};
}

// ---------------- K2: group gmax + global amax_sub ----------------
__global__ __launch_bounds__(256) void k_r1(const float* __restrict__ scale,
                                            char* __restrict__ ws) {
    const signed char* pmax8 = (const signed char*)(ws + PMAX_B);
    const signed char* pmin8 = (const signed char*)(ws + PMIN_B);
    float* gmv = (float*)(ws + GMV_B);
    float* sc  = (float*)(ws + SC_B);

    const int ci  = threadIdx.x & 31;
    const int sub = threadIdx.x >> 5;           // 0..7
    const int g   = blockIdx.x * 32 + ci;       // 256 blocks x 32 groups

    int mx = -128, mn = 127;
    for (int jc = sub; jc < NJC; jc += 8) {
        const size_t idx = (size_t)jc * NG + g;
        mx = max(mx, (int)pmax8[idx]);
        mn = min(mn, (int)pmin8[idx]);
    }
    __shared__ int smx[8][32], smn[8][32];
    smx[sub][ci] = mx; smn[sub][ci] = mn;
    __syncthreads();
    for (int off = 4; off; off >>= 1) {
        if (sub < off) {
            smx[sub][ci] = max(smx[sub][ci], smx[sub + off][ci]);
            smn[sub][ci] = min(smn[sub][ci], smn[sub + off][ci]);
        }
        __syncthreads();
    }
    __shared__ float sd[32];
    if (sub == 0) {
        const float s = scale[0];
        gmv[g] = (float)smx[0][ci];             // stored as CODE (consumers *s)
        sd[ci] = fminf(12.0f, (float)smx[0][ci] * s - (float)smn[0][ci] * s);
    }
    __syncthreads();
    if (threadIdx.x == 0) {
        float m = sd[0];
#pragma unroll
        for (int i = 1; i < 32; ++i) m = fmaxf(m, sd[i]);
        atomicMax(reinterpret_cast<unsigned int*>(sc + 0), __float_as_uint(m));
    }
}

// ---------------- K3: column-slab group sums + global max/min s ----------------
// 512 blocks x 512 thr; block owns 16 consecutive groups (same b).
// Tree identical to R8 phase B (validated: absmax matched the row-chunk path).
template <bool UC>
__global__ __launch_bounds__(512) void k_p2(const float* __restrict__ x,
                                            const float* __restrict__ scale,
                                            char* __restrict__ ws) {
    const int g0 = blockIdx.x * 16;             // 16 groups
    const int b  = g0 >> 10;
    const int cb = g0 & 1023;
    const int t  = threadIdx.x;
    const int cq = t & 3;                       // col group (4 cols)
    const int rs = t >> 2;                      // 0..127 row slot
    const int w  = t >> 6;                      // wave 0..7
    const int l  = t & 63;

    const float s = scale[0];
    const float sinv = 1.0f / s;
    float* sc   = (float*)(ws + SC_B);
    float* gmv  = (float*)(ws + GMV_B);
    float* sarr = (float*)(ws + SARR_B);
    const signed char* codes = (const signed char*)(ws + CODES_B);

    const float amax = fmaxf(sc[0], 1e-9f);
    const float ssub = amax / 32767.0f;
    const float ssub_inv = 1.0f / ssub;
    const f4 gmc = *reinterpret_cast<const f4*>(gmv + g0 + cq * 4);
    const f4 gm  = {gmc[0] * s, gmc[1] * s, gmc[2] * s, gmc[3] * s};

    const size_t base = ((size_t)(b * Jdim + rs)) * Cdim + (size_t)(cb + cq * 4);

    f4 acc = {0.f, 0.f, 0.f, 0.f};
#pragma unroll 8
    for (int k = 0; k < 32; ++k) {              // rows rs, rs+128, ...
        float xq0, xq1, xq2, xq3;
        if (UC) {
            const c4 q = *reinterpret_cast<const c4*>(codes + base + (size_t)k * 128 * Cdim);
            xq0 = (float)q[0] * s; xq1 = (float)q[1] * s;
            xq2 = (float)q[2] * s; xq3 = (float)q[3] * s;
        } else {
            const f4 v = *reinterpret_cast<const f4*>(x + base + (size_t)k * 128 * Cdim);
            xq0 = code8f(v[0], sinv) * s; xq1 = code8f(v[1], sinv) * s;
            xq2 = code8f(v[2], sinv) * s; xq3 = code8f(v[3], sinv) * s;
        }
        acc[0] += eq_from(xq0, gm[0], ssub_inv, ssub);
        acc[1] += eq_from(xq1, gm[1], ssub_inv, ssub);
        acc[2] += eq_from(xq2, gm[2], ssub_inv, ssub);
        acc[3] += eq_from(xq3, gm[3], ssub_inv, ssub);
    }
    // wave reduce over rs bits (lane bits 2..5)
#pragma unroll
    for (int off = 4; off < 64; off <<= 1) acc = add4v(acc, shfl_xor4(acc, off));

    __shared__ f4 lA[8][4];
    __shared__ float smx8[8], smn8[8];
    if (l < 4) lA[w][l] = acc;
    __syncthreads();
    if (w == 0 && l < 32) {
        const int wi = l >> 2, cg = l & 3;      // wi 0..7
        f4 tsum = lA[wi][cg];
#pragma unroll
        for (int off = 4; off < 32; off <<= 1) tsum = add4v(tsum, shfl_xor4(tsum, off));
        if (l < 4) {
            *reinterpret_cast<f4*>(sarr + g0 + l * 4) = tsum;
            float mx = fmaxf(fmaxf(tsum[0], tsum[1]), fmaxf(tsum[2], tsum[3]));
            float mn = fminf(fminf(tsum[0], tsum[1]), fminf(tsum[2], tsum[3]));
            mx = fmaxf(mx, __shfl_xor(mx, 1)); mn = fminf(mn, __shfl_xor(mn, 1));
            mx = fmaxf(mx, __shfl_xor(mx, 2)); mn = fminf(mn, __shfl_xor(mn, 2));
            if (l == 0) { smx8[0] = mx; smn8[0] = mn; }
        }
    }
    __syncthreads();
    if (t == 0) {
        atomicMax(reinterpret_cast<unsigned int*>(sc + 1), __float_as_uint(smx8[0]));
        atomicMin(reinterpret_cast<unsigned int*>(sc + 2), __float_as_uint(smn8[0]));
    }
}

// ---------------- K4: output pass ----------------
template <bool UC>
__global__ __launch_bounds__(256) void k_p3(const float* __restrict__ x,
                                            const float* __restrict__ scale,
                                            const char* __restrict__ ws,
                                            float* __restrict__ out) {
    const int b  = blockIdx.x / NJC;
    const int jc = blockIdx.x % NJC;
    const int c0 = threadIdx.x * 4;
    const float s = scale[0];
    const float sinv = 1.0f / s;
    const float* sc   = (const float*)(ws + SC_B);
    const float* gmv  = (const float*)(ws + GMV_B);
    const float* sarr = (const float*)(ws + SARR_B);
    const signed char* codes = (const signed char*)(ws + CODES_B);

    const float amax = fmaxf(sc[0], 1e-9f);
    const float ssub = amax / 32767.0f;
    const float ssub_inv = 1.0f / ssub;

    const float max_s = sc[1];
    const float min_s = sc[2];
    // fq monotone: min s_q = fq(min s); max r = 1/min s_q; max r_q = fq(max r)
    const float scale_s = fmaxf(max_s, 1e-9f) / 32767.0f;
    const float ss_inv  = 1.0f / scale_s;
    const float minsq   = fminf(fmaxf(rintf(min_s * ss_inv), -32768.0f), 32767.0f) * scale_s;
    const float maxr    = 1.0f / minsq;
    const float scale_r = fmaxf(maxr, 1e-9f) / 32767.0f;
    const float sr_inv  = 1.0f / scale_r;
    const float maxrq   = fminf(fmaxf(rintf(maxr * sr_inv), -32768.0f), 32767.0f) * scale_r;
    const float scale_out = fmaxf(maxrq, 1e-9f) / 127.0f;
    const float so_inv  = 1.0f / scale_out;

    const f4 gmc = *reinterpret_cast<const f4*>(gmv + b * Cdim + c0);
    const f4 gm  = {gmc[0] * s, gmc[1] * s, gmc[2] * s, gmc[3] * s};
    const f4 s4  = *reinterpret_cast<const f4*>(sarr + b * Cdim + c0);

    f4 rq;
#pragma unroll
    for (int i = 0; i < 4; ++i) {
        float qv = fminf(fmaxf(rintf(s4[i] * ss_inv), -32768.0f), 32767.0f) * scale_s;
        rq[i] = fminf(fmaxf(rintf((1.0f / qv) * sr_inv), -32768.0f), 32767.0f) * scale_r;
    }

    const size_t base = ((size_t)(b * Jdim + jc * JC1)) * Cdim + c0;
#pragma unroll
    for (int r0 = 0; r0 < JC1; r0 += 8) {
        c4 qv[8];
        f4 xv[8];
#pragma unroll
        for (int j = 0; j < 8; ++j) {               // 8 loads in flight
            if (UC)
                qv[j] = *reinterpret_cast<const c4*>(codes + base + (size_t)(r0 + j) * Cdim);
            else
                xv[j] = *reinterpret_cast<const f4*>(x + base + (size_t)(r0 + j) * Cdim);
        }
#pragma unroll
        for (int j = 0; j < 8; ++j) {
            float xq0, xq1, xq2, xq3;
            if (UC) {
                xq0 = (float)qv[j][0] * s; xq1 = (float)qv[j][1] * s;
                xq2 = (float)qv[j][2] * s; xq3 = (float)qv[j][3] * s;
            } else {
                xq0 = code8f(xv[j][0], sinv) * s; xq1 = code8f(xv[j][1], sinv) * s;
                xq2 = code8f(xv[j][2], sinv) * s; xq3 = code8f(xv[j][3], sinv) * s;
            }
            const float e0 = eq_from(xq0, gm[0], ssub_inv, ssub) * rq[0];
            const float e1 = eq_from(xq1, gm[1], ssub_inv, ssub) * rq[1];
            const float e2 = eq_from(xq2, gm[2], ssub_inv, ssub) * rq[2];
            const float e3 = eq_from(xq3, gm[3], ssub_inv, ssub) * rq[3];
            f4 o;
            o[0] = fminf(fmaxf(rintf(e0 * so_inv), -128.0f), 127.0f) * scale_out;
            o[1] = fminf(fmaxf(rintf(e1 * so_inv), -128.0f), 127.0f) * scale_out;
            o[2] = fminf(fmaxf(rintf(e2 * so_inv), -128.0f), 127.0f) * scale_out;
            o[3] = fminf(fmaxf(rintf(e3 * so_inv), -128.0f), 127.0f) * scale_out;
            __builtin_nontemporal_store(o,
                reinterpret_cast<f4*>(out + base + (size_t)(r0 + j) * Cdim));
        }
    }
}

extern "C" void kernel_launch(void* const* d_in, const int* in_sizes, int n_in,
                              void* d_out, int out_size, void* d_ws, size_t ws_size,
                              hipStream_t stream) {
    const float* x     = (const float*)d_in[0];
    const float* scale = (const float*)d_in[1];
    float* out = (float*)d_out;
    char* ws   = (char*)d_ws;

    if (ws_size >= WS_FULL) {
        k_p1<true ><<<GRID1, 256, 0, stream>>>(x, scale, ws);
        k_r1<<<NG / 32, 256, 0, stream>>>(scale, ws);
        k_p2<true ><<<NG / 16, 512, 0, stream>>>(x, scale, ws);
        k_p3<true ><<<GRID1, 256, 0, stream>>>(x, scale, ws, out);
    } else {
        // no-codes fallback: recompute xq from x in K3/K4 (bit-identical)
        k_p1<false><<<GRID1, 256, 0, stream>>>(x, scale, ws);
        k_r1<<<NG / 32, 256, 0, stream>>>(scale, ws);
        k_p2<false><<<NG / 16, 512, 0, stream>>>(x, scale, ws);
        k_p3<false><<<GRID1, 256, 0, stream>>>(x, scale, ws, out);
    }
}